// Round 14
// baseline (289.561 us; speedup 1.0000x reference)
//
#include <hip/hip_runtime.h>
#include <cstdint>

// ---------------------------------------------------------------------------
// TileTask_62277025792545: bit-serial int8 conv emulation.
// R14: ABLATION ROUND (pre-committed after 5 structural nulls at ~31us).
// Five rep-surfaced probe variants of the R13 core take the rocprof top-5
// slots; the unchanged R13 k_main runs last and produces d_out.
//   V1: B+MFMA only   V2: no-MFMA   V3: no-B-read   V4: no-epilogue   V0: full
// DCE-proofing: opaque per-rep seeds (asm "+v"), keepalive on chain tails,
// "memory" clobber per rep. Probes only read ws; only k_main writes d_out.
// ---------------------------------------------------------------------------

typedef int i32x4  __attribute__((ext_vector_type(4)));
typedef int i32x16 __attribute__((ext_vector_type(16)));

#define XB_OFF   0u
#define XB_BYTES 4326400u                      // 4*130*130*64 u8, padded NHWC
#define WPK_OFF  XB_BYTES                      // packed i8 B-frags
#define WPK_BYTES 36864u                       // 18*2*64*16 i8

__global__ __launch_bounds__(256) void k_stage(const float* __restrict__ s_cast,
                                               const float* __restrict__ wsrc,
                                               uint8_t* __restrict__ ws) {
  const int blk = blockIdx.x, t = threadIdx.x;
  if (blk >= 656) {                            // ---- halo top/bottom rows ----
    const int hb = blk - 656;                  // 8 blocks: 4 b x {0,129}
    const int b = hb >> 1, r = (hb & 1) ? 129 : 0;
    uint8_t* base = ws + XB_OFF + ((size_t)(b * 130 + r) * 130) * 64;
    const uint4 z = {0, 0, 0, 0};
#pragma unroll
    for (int i = 0; i < 3; ++i) {
      const int s = i * 256 + t;
      if (s < 520) *(uint4*)(base + (size_t)s * 16) = z;
    }
    return;
  }
  if (blk >= 512) {                            // ---- weight pack path ----
    const int idx = (blk - 512) * 256 + t;
    const int i = idx & 15, l = (idx >> 4) & 63, gg = (idx >> 10) & 1,
              c = idx >> 11;
    const int k = c * 32 + (l >> 5) * 16 + i;
    const int tap = k >> 6, ci = k & 63;
    const int kh = tap / 3, kw = tap % 3;
    const int cco = gg * 32 + (l & 31);
    const float wv = wsrc[((cco * 64 + ci) * 3 + kh) * 3 + kw];
    ((int8_t*)(ws + WPK_OFF))[idx] = (int8_t)(int)wv;
    return;
  }
  const int b = blk >> 7, h = blk & 127;       // ---- cast path ----
  __shared__ uint8_t lds[128 * 68];
  const float* s0 = s_cast + ((size_t)(b * 64) * 128 + h) * 128;
#pragma unroll
  for (int ci0 = 0; ci0 < 64; ci0 += 2) {
    const int ci = ci0 + (t >> 7), w = t & 127;
    const float v = s0[ci * 16384 + w];
    lds[w * 68 + ci] = (uint8_t)((int)v & 0xFF);
  }
  __syncthreads();
  uint8_t* row = ws + XB_OFF + (((size_t)b * 130 + h + 1) * 130) * 64;
#pragma unroll
  for (int j = 0; j < 8; ++j) {
    const int f = j * 256 + t;
    const int w = f >> 4, ci4 = f & 15;
    const uint32_t val = *(const uint32_t*)&lds[w * 68 + ci4 * 4];
    *(uint32_t*)(row + 64 + (size_t)f * 4) = val;
  }
  if (t < 8) {
    const int col = (t < 4) ? 0 : 129, seg = t & 3;
    const uint4 z = {0, 0, 0, 0};
    *(uint4*)(row + (size_t)col * 64 + seg * 16) = z;
  }
}

// Shared geometry helpers for probe + real kernel (R13 layout).
#define XOFF(c) ((((c) >> 1) / 3) * 1280 + (((c) >> 1) % 3) * 64 + ((c)&1) * 32)

template <int VARIANT, int REPS>
__global__ __launch_bounds__(256, 3) void k_probe(
    const unsigned char* __restrict__ xb, const float* __restrict__ mgf,
    const float* __restrict__ gtf, const int8_t* __restrict__ wpk,
    const float* __restrict__ bias, const float* __restrict__ cti,
    const float* __restrict__ cts, const float* __restrict__ sti,
    const float* __restrict__ sts, const float* __restrict__ ati,
    const float* __restrict__ ats) {
  const int tid = threadIdx.x, lane = tid & 63, wg = tid >> 6;
  const int blk = blockIdx.x;
  const int wq = blk & 7, ho = (blk >> 3) & 63, b = blk >> 9;
  const int h0 = ho * 2, w0 = wq * 16;

  __shared__ uint8_t ldsx[4 * 20 * 64];
  __shared__ i32x4 wpkl[2304];
  __shared__ uint8_t mgt8[2][2][64][20];
  __shared__ float po_lds[8][65];

  // ---- staging identical to k_main ----
#pragma unroll
  for (int i = 0; i < 2; ++i) {
    const int s = i * 256 + tid;
    if (s < 288) {
      const int row = s / 72, rm = s - row * 72;
      const int col = rm >> 2, ci16 = rm & 3;
      const uint4 v = *(const uint4*)(
          xb + ((size_t)((b * 130 + h0 + row) * 130) + w0 + col) * 64 + ci16 * 16);
      *(uint4*)(ldsx + (row * 20 + col) * 64 + ci16 * 16) = v;
    }
  }
#pragma unroll
  for (int i = 0; i < 9; ++i) {
    const int s = i * 256 + tid;
    wpkl[s] = *(const i32x4*)(wpk + (size_t)s * 16);
  }
#pragma unroll
  for (int which = 0; which < 2; ++which) {
    const float* sp = which ? gtf : mgf;
#pragma unroll
    for (int i = 0; i < 2; ++i) {
      const int slot = i * 256 + tid;
      const int co = slot >> 3, r3 = slot & 7, hh = r3 >> 2, seg = r3 & 3;
      const float4 v = *(const float4*)(
          sp + ((size_t)((b * 64 + co) * 128 + h0 + hh)) * 128 + w0 + seg * 4);
      const uint32_t pk =
          ((uint32_t)((int)v.x & 0xFF)) | ((uint32_t)((int)v.y & 0xFF) << 8) |
          ((uint32_t)((int)v.z & 0xFF) << 16) | ((uint32_t)((int)v.w & 0xFF) << 24);
      *(uint32_t*)&mgt8[which][hh][co][seg * 4] = pk;
    }
  }

  const int pix = (lane & 31) >> 3;
  const int plane = lane & 7;
  const int khalf = lane >> 5;
  const int dh = pix >> 1, dw = pix & 1;
  const uint8_t* lbw = ldsx + ((dh * 20) + (wg * 4 + dw)) * 64 + khalf * 16;

  const int col = lane & 31;
  const float bs0 = bias[col], bs1 = bias[col + 32];
  const float cm0 = ldexpf(cti[col], (int)cts[col]);
  const float cm1 = ldexpf(cti[col + 32], (int)cts[col + 32]);
  const float sm = ldexpf(sti[0], (int)sts[0]);
  const float am = ldexpf(ati[0], (int)ats[0]);
  float pwl[4];
  pwl[0] = khalf ? 16.f : 1.f;
  pwl[1] = khalf ? 32.f : 2.f;
  pwl[2] = khalf ? 64.f : 4.f;
  pwl[3] = khalf ? -128.f : 8.f;

  __syncthreads();

#pragma unroll 1
  for (int rep = 0; rep < REPS; ++rep) {
    asm volatile("" ::: "memory");             // force LDS re-read per rep
    int seed = lane + rep;
    asm volatile("" : "+v"(seed));             // opaque per-rep value

    i32x16 acc[2][2] = {};
    int keep = 0;
#pragma unroll
    for (int c = 0; c < 18; ++c) {
      i32x4 B0, B1;
      if constexpr (VARIANT == 3) {            // no B-read
        B0[0] = seed; B0[1] = seed; B0[2] = seed; B0[3] = seed;
        B1[0] = seed ^ 1; B1[1] = seed; B1[2] = seed; B1[3] = seed;
      } else {
        B0 = wpkl[(c * 2 + 0) * 64 + lane];
        B1 = wpkl[(c * 2 + 1) * 64 + lane];
      }
#pragma unroll
      for (int q = 0; q < 2; ++q) {
        i32x4 av;
        if constexpr (VARIANT == 1) {          // no x-read / extract
          av[0] = seed; av[1] = seed ^ q; av[2] = seed; av[3] = seed;
        } else {
          const uint4 vv = *(const uint4*)(lbw + q * 128 + XOFF(c));
          av[0] = (int)((vv.x >> plane) & 0x01010101u);
          av[1] = (int)((vv.y >> plane) & 0x01010101u);
          av[2] = (int)((vv.z >> plane) & 0x01010101u);
          av[3] = (int)((vv.w >> plane) & 0x01010101u);
        }
        if constexpr (VARIANT == 2) {          // no MFMA
          keep ^= av[0] ^ B0[0] ^ B1[0];
        } else {
          acc[q][0] = __builtin_amdgcn_mfma_i32_32x32x32_i8(av, B0, acc[q][0], 0, 0, 0);
          acc[q][1] = __builtin_amdgcn_mfma_i32_32x32x32_i8(av, B1, acc[q][1], 0, 0, 0);
        }
      }
    }

    if constexpr (VARIANT == 2) {
      asm volatile("" ::"v"(keep));
    } else if constexpr (VARIANT == 0) {
      // full epilogue (writes po_lds; no global store in probe)
#pragma unroll
      for (int q = 0; q < 2; ++q) {
        const int wol = wg * 2 + q;
#pragma unroll
        for (int gg = 0; gg < 2; ++gg) {
          const float bs = gg ? bs1 : bs0;
          const float cm = gg ? cm1 : cm0;
          const int cc = gg * 32 + col;
          float psum[4];
#pragma unroll
          for (int px = 0; px < 4; ++px) {
            float s = 0.f;
#pragma unroll
            for (int j = 0; j < 4; ++j) {
              const float y = (float)acc[q][gg][px * 4 + j];
              const float qq = fminf(fmaxf(rintf(y * 0.5f), -128.f), 127.f);
              s = fmaf(pwl[j], 2.f * qq, s);
            }
            psum[px] = s;
          }
#pragma unroll
          for (int px = 0; px < 4; ++px) psum[px] += __shfl_xor(psum[px], 32);
          float po = -3.0e38f;
#pragma unroll
          for (int px = 0; px < 4; ++px) {
            const int ww = wol * 2 + (px & 1);
            const int hh = px >> 1;
            const float mgv = (float)(int)(signed char)mgt8[0][hh][cc][ww];
            const float gtv = (float)(int)(signed char)mgt8[1][hh][cc][ww];
            const float x1 = psum[px] + bs + mgv;
            const float x2 = fminf(fmaxf(rintf(x1 * cm), -128.f), 127.f);
            const float x3 = x2 + gtv;
            const float x4 = fminf(fmaxf(rintf(x3 * sm), -128.f), 127.f);
            const float x5 = fmaxf(x4, 0.f);
            const float x6 = fminf(fmaxf(rintf(x5 * am), -128.f), 127.f);
            po = fmaxf(po, x6);
          }
          if (lane < 32) po_lds[wol][cc] = po;
        }
      }
    } else {                                   // V1/V3/V4: keepalive acc chains
      int s = acc[0][0][0] ^ acc[0][1][0] ^ acc[1][0][0] ^ acc[1][1][0];
      asm volatile("" ::"v"(s));
    }
  }
}

// ---- real kernel: R13 verbatim ----
__global__ __launch_bounds__(256, 3) void k_main(
    const unsigned char* __restrict__ xb, const float* __restrict__ mgf,
    const float* __restrict__ gtf, const int8_t* __restrict__ wpk,
    const float* __restrict__ bias, const float* __restrict__ cti,
    const float* __restrict__ cts, const float* __restrict__ sti,
    const float* __restrict__ sts, const float* __restrict__ ati,
    const float* __restrict__ ats, float* __restrict__ outp) {
  const int tid = threadIdx.x, lane = tid & 63, wg = tid >> 6;
  const int blk = blockIdx.x;
  const int wq = blk & 7, ho = (blk >> 3) & 63, b = blk >> 9;
  const int h0 = ho * 2, w0 = wq * 16;

  __shared__ uint8_t ldsx[4 * 20 * 64];
  __shared__ i32x4 wpkl[2304];
  __shared__ uint8_t mgt8[2][2][64][20];
  __shared__ float po_lds[8][65];

#pragma unroll
  for (int i = 0; i < 2; ++i) {
    const int s = i * 256 + tid;
    if (s < 288) {
      const int row = s / 72, rm = s - row * 72;
      const int col = rm >> 2, ci16 = rm & 3;
      const uint4 v = *(const uint4*)(
          xb + ((size_t)((b * 130 + h0 + row) * 130) + w0 + col) * 64 + ci16 * 16);
      *(uint4*)(ldsx + (row * 20 + col) * 64 + ci16 * 16) = v;
    }
  }
#pragma unroll
  for (int i = 0; i < 9; ++i) {
    const int s = i * 256 + tid;
    wpkl[s] = *(const i32x4*)(wpk + (size_t)s * 16);
  }
#pragma unroll
  for (int which = 0; which < 2; ++which) {
    const float* sp = which ? gtf : mgf;
#pragma unroll
    for (int i = 0; i < 2; ++i) {
      const int slot = i * 256 + tid;
      const int co = slot >> 3, r3 = slot & 7, hh = r3 >> 2, seg = r3 & 3;
      const float4 v = *(const float4*)(
          sp + ((size_t)((b * 64 + co) * 128 + h0 + hh)) * 128 + w0 + seg * 4);
      const uint32_t pk =
          ((uint32_t)((int)v.x & 0xFF)) | ((uint32_t)((int)v.y & 0xFF) << 8) |
          ((uint32_t)((int)v.z & 0xFF) << 16) | ((uint32_t)((int)v.w & 0xFF) << 24);
      *(uint32_t*)&mgt8[which][hh][co][seg * 4] = pk;
    }
  }

  const int pix = (lane & 31) >> 3;
  const int plane = lane & 7;
  const int khalf = lane >> 5;
  const int dh = pix >> 1, dw = pix & 1;
  const uint8_t* lbw = ldsx + ((dh * 20) + (wg * 4 + dw)) * 64 + khalf * 16;

  const int col = lane & 31;
  const float bs0 = bias[col], bs1 = bias[col + 32];
  const float cm0 = ldexpf(cti[col], (int)cts[col]);
  const float cm1 = ldexpf(cti[col + 32], (int)cts[col + 32]);
  const float sm = ldexpf(sti[0], (int)sts[0]);
  const float am = ldexpf(ati[0], (int)ats[0]);
  float pwl[4];
  pwl[0] = khalf ? 16.f : 1.f;
  pwl[1] = khalf ? 32.f : 2.f;
  pwl[2] = khalf ? 64.f : 4.f;
  pwl[3] = khalf ? -128.f : 8.f;

  __syncthreads();

  i32x16 acc[2][2] = {};
#pragma unroll
  for (int c = 0; c < 18; ++c) {
    const i32x4 B0 = wpkl[(c * 2 + 0) * 64 + lane];
    const i32x4 B1 = wpkl[(c * 2 + 1) * 64 + lane];
#pragma unroll
    for (int q = 0; q < 2; ++q) {
      const uint4 vv = *(const uint4*)(lbw + q * 128 + XOFF(c));
      i32x4 av;
      av[0] = (int)((vv.x >> plane) & 0x01010101u);
      av[1] = (int)((vv.y >> plane) & 0x01010101u);
      av[2] = (int)((vv.z >> plane) & 0x01010101u);
      av[3] = (int)((vv.w >> plane) & 0x01010101u);
      acc[q][0] = __builtin_amdgcn_mfma_i32_32x32x32_i8(av, B0, acc[q][0], 0, 0, 0);
      acc[q][1] = __builtin_amdgcn_mfma_i32_32x32x32_i8(av, B1, acc[q][1], 0, 0, 0);
    }
  }

#pragma unroll
  for (int q = 0; q < 2; ++q) {
    const int wol = wg * 2 + q;
#pragma unroll
    for (int gg = 0; gg < 2; ++gg) {
      const float bs = gg ? bs1 : bs0;
      const float cm = gg ? cm1 : cm0;
      const int cc = gg * 32 + col;
      float psum[4];
#pragma unroll
      for (int px = 0; px < 4; ++px) {
        float s = 0.f;
#pragma unroll
        for (int j = 0; j < 4; ++j) {
          const float y = (float)acc[q][gg][px * 4 + j];
          const float qq = fminf(fmaxf(rintf(y * 0.5f), -128.f), 127.f);
          s = fmaf(pwl[j], 2.f * qq, s);
        }
        psum[px] = s;
      }
#pragma unroll
      for (int px = 0; px < 4; ++px) psum[px] += __shfl_xor(psum[px], 32);

      float po = -3.0e38f;
#pragma unroll
      for (int px = 0; px < 4; ++px) {
        const int ww = wol * 2 + (px & 1);
        const int hh = px >> 1;
        const float mgv = (float)(int)(signed char)mgt8[0][hh][cc][ww];
        const float gtv = (float)(int)(signed char)mgt8[1][hh][cc][ww];
        const float x1 = psum[px] + bs + mgv;
        const float x2 = fminf(fmaxf(rintf(x1 * cm), -128.f), 127.f);
        const float x3 = x2 + gtv;
        const float x4 = fminf(fmaxf(rintf(x3 * sm), -128.f), 127.f);
        const float x5 = fmaxf(x4, 0.f);
        const float x6 = fminf(fmaxf(rintf(x5 * am), -128.f), 127.f);
        po = fmaxf(po, x6);
      }
      if (lane < 32) po_lds[wol][cc] = po;
    }
  }

  __syncthreads();
  {
    const int tco = tid >> 2, seg = tid & 3;
    float2 v;
    v.x = po_lds[seg * 2 + 0][tco];
    v.y = po_lds[seg * 2 + 1][tco];
    float* dst = outp + (((size_t)(b * 64 + tco)) * 64 + ho) * 64 + wq * 8 + seg * 2;
    *(float2*)dst = v;
  }
}
#undef XOFF

extern "C" void kernel_launch(void* const* d_in, const int* in_sizes, int n_in,
                              void* d_out, int out_size, void* d_ws, size_t ws_size,
                              hipStream_t stream) {
  const float* cast_in = (const float*)d_in[0];
  const float* merge_in = (const float*)d_in[1];
  const float* gather_in = (const float*)d_in[2];
  const float* conv_w = (const float*)d_in[3];
  const float* conv_b = (const float*)d_in[4];
  const float* cti = (const float*)d_in[5];
  const float* cts = (const float*)d_in[6];
  const float* sti = (const float*)d_in[7];
  const float* sts = (const float*)d_in[8];
  const float* ati = (const float*)d_in[9];
  const float* ats = (const float*)d_in[10];

  uint8_t* ws = (uint8_t*)d_ws;
  uint8_t* xb = ws + XB_OFF;
  int8_t* wpk = (int8_t*)(ws + WPK_OFF);

  k_stage<<<664, 256, 0, stream>>>(cast_in, conv_w, ws);
  // ---- probes (read-only; surfaced above the 39-41us poison fills) ----
  k_probe<1, 6><<<2048, 256, 0, stream>>>(xb, merge_in, gather_in, wpk, conv_b,
                                          cti, cts, sti, sts, ati, ats);
  k_probe<2, 6><<<2048, 256, 0, stream>>>(xb, merge_in, gather_in, wpk, conv_b,
                                          cti, cts, sti, sts, ati, ats);
  k_probe<3, 5><<<2048, 256, 0, stream>>>(xb, merge_in, gather_in, wpk, conv_b,
                                          cti, cts, sti, sts, ati, ats);
  k_probe<4, 4><<<2048, 256, 0, stream>>>(xb, merge_in, gather_in, wpk, conv_b,
                                          cti, cts, sti, sts, ati, ats);
  k_probe<0, 3><<<2048, 256, 0, stream>>>(xb, merge_in, gather_in, wpk, conv_b,
                                          cti, cts, sti, sts, ati, ats);
  // ---- real kernel (R13 verbatim) ----
  k_main<<<2048, 256, 0, stream>>>(xb, merge_in, gather_in, wpk, conv_b, cti,
                                   cts, sti, sts, ati, ats, (float*)d_out);
}

// Round 15
// 36.006 us; speedup vs baseline: 8.0420x; 8.0420x over previous
//
#include <hip/hip_runtime.h>
#include <cstdint>

// ---------------------------------------------------------------------------
// TileTask_62277025792545: bit-serial int8 conv emulation.
//   conv: 8 bit-planes of cast_in (two's complement), each 3x3x64->64 conv,
//   per-plane q = 2*clip(rne(y/2),-128,127), recombine with [1,2,..,64,-128],
//   +bias, +merge, quant(cmult), +gather, quant(0.75), relu, quant(1), pool2x2.
// Implementation: implicit-GEMM MFMA (i8), M=(pixel,plane), N=cout, K=ci*9=576.
// R15: PERSISTENT BLOCKS. R14 ablation: core floor (B+MFMA) = 12.3us/rep at
// MfmaUtil 71% (8.8us pure pipe); full core ~16.8; the rest of k_main's ~33us
// is per-block setup dominated by staging 36KB wpkl per block (2048x in R13).
// Now grid=768 (3/CU resident), wpkl staged once per block, each block loops
// over 2-3 tiles (8 tiles/CU uniformly); per-tile x/mgt8 staged via T14
// reg-prefetch (issue next tile's loads under current tile's K-loop).
// ---------------------------------------------------------------------------

typedef int i32x4  __attribute__((ext_vector_type(4)));
typedef int i32x16 __attribute__((ext_vector_type(16)));

#define XB_OFF   0u
#define XB_BYTES 4326400u                      // 4*130*130*64 u8, padded NHWC
#define WPK_OFF  XB_BYTES                      // packed i8 B-frags
#define WPK_BYTES 36864u                       // 18*2*64*16 i8

// cast_in NCHW f32 -> NHWC bytes with halo (130x130), + weight pack + halo
// row zeroing. Blocks 0..511 cast, 512..655 pack, 656..663 halo rows. ~2.5us.
__global__ __launch_bounds__(256) void k_stage(const float* __restrict__ s_cast,
                                               const float* __restrict__ wsrc,
                                               uint8_t* __restrict__ ws) {
  const int blk = blockIdx.x, t = threadIdx.x;
  if (blk >= 656) {                            // ---- halo top/bottom rows ----
    const int hb = blk - 656;                  // 8 blocks: 4 b x {0,129}
    const int b = hb >> 1, r = (hb & 1) ? 129 : 0;
    uint8_t* base = ws + XB_OFF + ((size_t)(b * 130 + r) * 130) * 64;
    const uint4 z = {0, 0, 0, 0};
#pragma unroll
    for (int i = 0; i < 3; ++i) {
      const int s = i * 256 + t;
      if (s < 520) *(uint4*)(base + (size_t)s * 16) = z;
    }
    return;
  }
  if (blk >= 512) {                            // ---- weight pack path ----
    const int idx = (blk - 512) * 256 + t;     // covers exactly 36864
    const int i = idx & 15, l = (idx >> 4) & 63, gg = (idx >> 10) & 1,
              c = idx >> 11;
    const int k = c * 32 + (l >> 5) * 16 + i;  // k = tap*64 + ci
    const int tap = k >> 6, ci = k & 63;
    const int kh = tap / 3, kw = tap % 3;
    const int cco = gg * 32 + (l & 31);
    const float wv = wsrc[((cco * 64 + ci) * 3 + kh) * 3 + kw];
    ((int8_t*)(ws + WPK_OFF))[idx] = (int8_t)(int)wv;
    return;
  }
  const int b = blk >> 7, h = blk & 127;       // ---- cast path ----
  __shared__ uint8_t lds[128 * 68];
  const float* s0 = s_cast + ((size_t)(b * 64) * 128 + h) * 128;
#pragma unroll
  for (int ci0 = 0; ci0 < 64; ci0 += 2) {
    const int ci = ci0 + (t >> 7), w = t & 127;
    const float v = s0[ci * 16384 + w];        // coalesced over w
    lds[w * 68 + ci] = (uint8_t)((int)v & 0xFF);
  }
  __syncthreads();
  uint8_t* row = ws + XB_OFF + (((size_t)b * 130 + h + 1) * 130) * 64;
#pragma unroll
  for (int j = 0; j < 8; ++j) {
    const int f = j * 256 + t;
    const int w = f >> 4, ci4 = f & 15;
    const uint32_t val = *(const uint32_t*)&lds[w * 68 + ci4 * 4];
    *(uint32_t*)(row + 64 + (size_t)f * 4) = val;
  }
  if (t < 8) {
    const int col = (t < 4) ? 0 : 129, seg = t & 3;
    const uint4 z = {0, 0, 0, 0};
    *(uint4*)(row + (size_t)col * 64 + seg * 16) = z;
  }
}

__global__ __launch_bounds__(256, 3) void k_main(
    const unsigned char* __restrict__ xb, const float* __restrict__ mgf,
    const float* __restrict__ gtf, const int8_t* __restrict__ wpk,
    const float* __restrict__ bias, const float* __restrict__ cti,
    const float* __restrict__ cts, const float* __restrict__ sti,
    const float* __restrict__ sts, const float* __restrict__ ati,
    const float* __restrict__ ats, float* __restrict__ outp) {
  const int tid = threadIdx.x, lane = tid & 63, wg = tid >> 6;   // 4 waves

  __shared__ uint8_t ldsx[4 * 20 * 64];        // x strip: [4 rows][20 cols][64]
  __shared__ i32x4 wpkl[2304];                 // all B-frags (36,864 B)
  __shared__ uint8_t mgt8[2][2][64][20];       // mg/gt int8: [t][hh][co][w+pad]
  __shared__ float po_lds[8][65];              // pooled out: [wo_local][co+pad]

  // ---- stage ALL B frags ONCE per persistent block ----
#pragma unroll
  for (int i = 0; i < 9; ++i) {
    const int s = i * 256 + tid;
    wpkl[s] = *(const i32x4*)(wpk + (size_t)s * 16);
  }

  // ---- tile-invariant LDS write targets ----
  const int xrow0 = tid / 72, xrm0 = tid - xrow0 * 72;
  const int xcol0 = xrm0 >> 2, xci0 = xrm0 & 3;
  uint8_t* const xw0 = ldsx + (xrow0 * 20 + xcol0) * 64 + xci0 * 16;
  const int xs1 = 256 + tid;                   // second x seg (tid<32 only)
  const int xrow1 = xs1 / 72, xrm1 = xs1 - xrow1 * 72;
  const int xcol1 = xrm1 >> 2, xci1 = xrm1 & 3;
  uint8_t* const xw1 = ldsx + (xrow1 * 20 + xcol1) * 64 + xci1 * 16;
  const int co0 = tid >> 3, hh0 = (tid & 7) >> 2, sg0 = tid & 3;
  const int co1 = 32 + (tid >> 3);             // slot 256+tid
  uint32_t* const mw00 = (uint32_t*)&mgt8[0][hh0][co0][sg0 * 4];
  uint32_t* const mw01 = (uint32_t*)&mgt8[0][hh0][co1][sg0 * 4];
  uint32_t* const mw10 = (uint32_t*)&mgt8[1][hh0][co0][sg0 * 4];
  uint32_t* const mw11 = (uint32_t*)&mgt8[1][hh0][co1][sg0 * 4];

  // ---- per-lane constants ----
  const int pix = (lane & 31) >> 3;            // A row = pix*8 + plane
  const int plane = lane & 7;
  const int khalf = lane >> 5;
  const int dh = pix >> 1, dw = pix & 1;
  const uint8_t* lbw = ldsx + ((dh * 20) + (wg * 4 + dw)) * 64 + khalf * 16;

  const int col = lane & 31;
  const float bs0 = bias[col], bs1 = bias[col + 32];
  const float cm0 = ldexpf(cti[col], (int)cts[col]);        // exact: i * 2^s
  const float cm1 = ldexpf(cti[col + 32], (int)cts[col + 32]);
  const float sm = ldexpf(sti[0], (int)sts[0]);
  const float am = ldexpf(ati[0], (int)ats[0]);
  float pwl[4];
  pwl[0] = khalf ? 16.f : 1.f;
  pwl[1] = khalf ? 32.f : 2.f;
  pwl[2] = khalf ? 64.f : 4.f;
  pwl[3] = khalf ? -128.f : 8.f;

  // ---- T14 reg-prefetch state + loader ----
  uint4 xr0, xr1;
  float4 m00, m01, m10, m11;
  auto load_tile = [&](int T) {
    const int wq_ = T & 7, ho_ = (T >> 3) & 63, b_ = T >> 9;
    const int h0_ = ho_ * 2, w0_ = wq_ * 16;
    xr0 = *(const uint4*)(
        xb + ((size_t)((b_ * 130 + h0_ + xrow0) * 130) + w0_ + xcol0) * 64 + xci0 * 16);
    if (tid < 32)
      xr1 = *(const uint4*)(
          xb + ((size_t)((b_ * 130 + h0_ + xrow1) * 130) + w0_ + xcol1) * 64 + xci1 * 16);
    m00 = *(const float4*)(mgf + ((size_t)((b_ * 64 + co0) * 128 + h0_ + hh0)) * 128 + w0_ + sg0 * 4);
    m01 = *(const float4*)(mgf + ((size_t)((b_ * 64 + co1) * 128 + h0_ + hh0)) * 128 + w0_ + sg0 * 4);
    m10 = *(const float4*)(gtf + ((size_t)((b_ * 64 + co0) * 128 + h0_ + hh0)) * 128 + w0_ + sg0 * 4);
    m11 = *(const float4*)(gtf + ((size_t)((b_ * 64 + co1) * 128 + h0_ + hh0)) * 128 + w0_ + sg0 * 4);
  };
  auto pack8 = [](const float4& v) -> uint32_t {
    return ((uint32_t)((int)v.x & 0xFF)) | ((uint32_t)((int)v.y & 0xFF) << 8) |
           ((uint32_t)((int)v.z & 0xFF) << 16) | ((uint32_t)((int)v.w & 0xFF) << 24);
  };

  load_tile(blockIdx.x);                       // prologue loads

#pragma unroll 1
  for (int t = blockIdx.x; t < 2048; t += 768) {
    const int wq = t & 7, ho = (t >> 3) & 63, b = t >> 9;   // current tile
    __syncthreads();                           // prev tile's LDS reads done
    *(uint4*)xw0 = xr0;
    if (tid < 32) *(uint4*)xw1 = xr1;
    *mw00 = pack8(m00);
    *mw01 = pack8(m01);
    *mw10 = pack8(m10);
    *mw11 = pack8(m11);
    if (t + 768 < 2048) load_tile(t + 768);    // T14: issue early, hide under K
    __syncthreads();                           // tile LDS ready

    // ---- K-outer: per chunk, B0/B1 once, 2 quads x 2 g = 4 MFMAs ----
#define XOFF(c) ((((c) >> 1) / 3) * 1280 + (((c) >> 1) % 3) * 64 + ((c)&1) * 32)
    i32x16 acc[2][2] = {};                     // [quad][g]
#pragma unroll
    for (int c = 0; c < 18; ++c) {
      const i32x4 B0 = wpkl[(c * 2 + 0) * 64 + lane];   // contiguous 1KB/wave
      const i32x4 B1 = wpkl[(c * 2 + 1) * 64 + lane];
#pragma unroll
      for (int q = 0; q < 2; ++q) {
        const uint4 vv = *(const uint4*)(lbw + q * 128 + XOFF(c));
        i32x4 av;                              // bit-plane extract IS the frag
        av[0] = (int)((vv.x >> plane) & 0x01010101u);
        av[1] = (int)((vv.y >> plane) & 0x01010101u);
        av[2] = (int)((vv.z >> plane) & 0x01010101u);
        av[3] = (int)((vv.w >> plane) & 0x01010101u);
        acc[q][0] = __builtin_amdgcn_mfma_i32_32x32x32_i8(av, B0, acc[q][0], 0, 0, 0);
        acc[q][1] = __builtin_amdgcn_mfma_i32_32x32x32_i8(av, B1, acc[q][1], 0, 0, 0);
      }
    }
#undef XOFF

    // ---- epilogue: reg j -> pixel=j>>2, plane=(j&3)+4*khalf ----
#pragma unroll
    for (int q = 0; q < 2; ++q) {
      const int wol = wg * 2 + q;
#pragma unroll
      for (int gg = 0; gg < 2; ++gg) {
        const float bs = gg ? bs1 : bs0;
        const float cm = gg ? cm1 : cm0;
        const int cc = gg * 32 + col;
        float psum[4];
#pragma unroll
        for (int px = 0; px < 4; ++px) {
          float s = 0.f;
#pragma unroll
          for (int j = 0; j < 4; ++j) {
            const float y = (float)acc[q][gg][px * 4 + j];
            const float qq = fminf(fmaxf(rintf(y * 0.5f), -128.f), 127.f);
            s = fmaf(pwl[j], 2.f * qq, s);     // plane_w * 2*clip(rne(y/2))
          }
          psum[px] = s;
        }
#pragma unroll
        for (int px = 0; px < 4; ++px)         // combine plane halves
          psum[px] += __shfl_xor(psum[px], 32);

        float po = -3.0e38f;
#pragma unroll
        for (int px = 0; px < 4; ++px) {
          const int ww = wol * 2 + (px & 1);
          const int hh = px >> 1;
          const float mgv = (float)(int)(signed char)mgt8[0][hh][cc][ww];
          const float gtv = (float)(int)(signed char)mgt8[1][hh][cc][ww];
          const float x1 = psum[px] + bs + mgv;
          const float x2 = fminf(fmaxf(rintf(x1 * cm), -128.f), 127.f);
          const float x3 = x2 + gtv;
          const float x4 = fminf(fmaxf(rintf(x3 * sm), -128.f), 127.f);
          const float x5 = fmaxf(x4, 0.f);
          const float x6 = fminf(fmaxf(rintf(x5 * am), -128.f), 127.f);
          po = fmaxf(po, x6);                  // 2x2 maxpool, in-lane
        }
        if (lane < 32) po_lds[wol][cc] = po;   // conflict-free (stride 1)
      }
    }

    __syncthreads();                           // po_lds ready
    {                                          // NCHW store, 8B coalesced
      const int tco = tid >> 2, seg = tid & 3;
      float2 v;
      v.x = po_lds[seg * 2 + 0][tco];
      v.y = po_lds[seg * 2 + 1][tco];
      *(float2*)(outp + (((size_t)(b * 64 + tco)) * 64 + ho) * 64 + wq * 8 +
                 seg * 2) = v;
    }
  }
}

extern "C" void kernel_launch(void* const* d_in, const int* in_sizes, int n_in,
                              void* d_out, int out_size, void* d_ws, size_t ws_size,
                              hipStream_t stream) {
  const float* cast_in = (const float*)d_in[0];
  const float* merge_in = (const float*)d_in[1];
  const float* gather_in = (const float*)d_in[2];
  const float* conv_w = (const float*)d_in[3];
  const float* conv_b = (const float*)d_in[4];
  const float* cti = (const float*)d_in[5];
  const float* cts = (const float*)d_in[6];
  const float* sti = (const float*)d_in[7];
  const float* sts = (const float*)d_in[8];
  const float* ati = (const float*)d_in[9];
  const float* ats = (const float*)d_in[10];

  uint8_t* ws = (uint8_t*)d_ws;
  uint8_t* xb = ws + XB_OFF;
  int8_t* wpk = (int8_t*)(ws + WPK_OFF);

  k_stage<<<664, 256, 0, stream>>>(cast_in, conv_w, ws);
  k_main<<<768, 256, 0, stream>>>(xb, merge_in, gather_in, wpk, conv_b, cti,
                                  cts, sti, sts, ati, ats, (float*)d_out);
}